// Round 4
// baseline (3823.965 us; speedup 1.0000x reference)
//
#include <hip/hip_runtime.h>
#include <stdint.h>

typedef _Float16 f16;
typedef _Float16 f16x8 __attribute__((ext_vector_type(8)));
typedef short bf16x8 __attribute__((ext_vector_type(8)));
typedef float f32x4 __attribute__((ext_vector_type(4)));

#define H_ 1024
#define NG_ 4096
#define F_ 512
#define B_ 64
#define T_ 128
#define CHUNK_ 16
#define NOP_ 640
#define NO_ 513
#define NBLK_R 256

// Hamilton block structure: W[p-block(in)][q-block(out)] = sign * comp
__constant__ int c_comp[16] = {0,1,2,3, 1,0,3,2, 2,3,0,1, 3,2,1,0};
__constant__ float c_sgnf[16] = {1,1,1,1, -1,1,1,-1, -1,-1,1,1, -1,1,-1,1};

__device__ __forceinline__ float bf2f(unsigned short u){
  union { unsigned int i; float f; } v; v.i = ((unsigned int)u) << 16; return v.f;
}
__device__ __forceinline__ unsigned short f2bf(float f){
  union { float f; unsigned int i; } v; v.f = f;
  return (unsigned short)((v.i + 0x7fffu + ((v.i >> 16) & 1u)) >> 16);
}
__device__ __forceinline__ float ldin(const void* p, int i, int f){
  return f ? ((const float*)p)[i] : bf2f(((const unsigned short*)p)[i]);
}
__device__ __forceinline__ float sigm(float x){ return 1.f / (1.f + __expf(-x)); }
__device__ __forceinline__ float tanh_(float x){
  float ax = fabsf(x);
  float e = __expf(-2.f * ax);
  float t = (1.f - e) / (1.f + e);
  return x < 0.f ? -t : t;
}

__global__ void detect_kernel(const unsigned short* __restrict__ xu, int* __restrict__ flag){
  __shared__ int zc, wc;
  if (threadIdx.x == 0){ zc = 0; wc = 0; }
  __syncthreads();
  unsigned short u = xu[2 * threadIdx.x];
  int e = (u >> 7) & 0xFF;
  bool z = (u & 0x7FFF) == 0;
  bool wild = !z && (e < 67 || e > 150);
  if (z) atomicAdd(&zc, 1);
  if (wild) atomicAdd(&wc, 1);
  __syncthreads();
  if (threadIdx.x == 0) *flag = (zc >= 128 || wc >= 64) ? 1 : 0;
}

#define XCHUNK_ELEMS (CHUNK_*B_*F_)   // 524288
__global__ void convert_x(const void* __restrict__ x, int elem_off,
                          const int* __restrict__ flag,
                          unsigned short* __restrict__ Xc){
  int f = *flag;
  int i = blockIdx.x * blockDim.x + threadIdx.x;
  int stride = gridDim.x * blockDim.x;
  for (; i < XCHUNK_ELEMS; i += stride) {
    int si = elem_off + i;
    Xc[i] = f ? f2bf(((const float*)x)[si]) : ((const unsigned short*)x)[si];
  }
}

#define WX_ELEMS (NG_*F_)
#define U_ELEMS  (NG_*H_)
#define FCO_ELEMS (NOP_*H_)
#define BIAS_ELEMS NG_
#define OB_ELEMS NOP_
#define PACK_TOTAL (WX_ELEMS + U_ELEMS + FCO_ELEMS + BIAS_ELEMS + OB_ELEMS)

__global__ void pack_kernel(
    const void* __restrict__ wf, const void* __restrict__ wi,
    const void* __restrict__ wo, const void* __restrict__ wc,
    const void* __restrict__ bfv, const void* __restrict__ biv,
    const void* __restrict__ bov, const void* __restrict__ bcv,
    const void* __restrict__ uf, const void* __restrict__ ui,
    const void* __restrict__ uo, const void* __restrict__ uc,
    const void* __restrict__ fcw, const void* __restrict__ fcb,
    const int* __restrict__ flag,
    unsigned short* __restrict__ Wx, f16* __restrict__ U, f16* __restrict__ Fco,
    float* __restrict__ bias, float* __restrict__ ob)
{
  const int fl = *flag;
  int i = blockIdx.x * blockDim.x + threadIdx.x;
  if (i < WX_ELEMS) {
    int n = i >> 9, k = i & 511;
    int g = n >> 10, nn = n & 1023;
    int q = nn >> 8, be = nn & 255;
    int p = k >> 7, al = k & 127;
    const void* w = (g==0) ? wf : (g==1) ? wi : (g==2) ? wo : wc;
    int pq = p*4 + q;
    Wx[i] = f2bf(c_sgnf[pq] * ldin(w, c_comp[pq]*32768 + al*256 + be, fl));
    return;
  }
  i -= WX_ELEMS;
  if (i < U_ELEMS) {
    int n = i >> 10, k = i & 1023;
    int g = n >> 10;
    int q = (n & 1023) >> 8, be = n & 255;
    int p = k >> 8, al = k & 255;
    const void* u = (g==0) ? uf : (g==1) ? ui : (g==2) ? uo : uc;
    int pq = p*4 + q;
    U[i] = (f16)(c_sgnf[pq] * ldin(u, c_comp[pq]*65536 + al*256 + be, fl));
    return;
  }
  i -= U_ELEMS;
  if (i < FCO_ELEMS) {
    int n = i >> 10, k = i & 1023;
    Fco[i] = (n < NO_) ? (f16)ldin(fcw, k*NO_ + n, fl) : (f16)0.f;
    return;
  }
  i -= FCO_ELEMS;
  if (i < BIAS_ELEMS) {
    int g = i >> 10;
    const void* b = (g==0) ? bfv : (g==1) ? biv : (g==2) ? bov : bcv;
    bias[i] = ldin(b, i & 1023, fl);
    return;
  }
  i -= BIAS_ELEMS;
  if (i < OB_ELEMS) {
    ob[i] = (i < NO_) ? ldin(fcb, i, fl) : 0.f;
  }
}

// G = Xc @ Wx^T-layout : M=1024, N=4096, K=512, bf16 MFMA, f16 store
__global__ __launch_bounds__(256) void gemm_g(
    const unsigned short* __restrict__ X,
    const unsigned short* __restrict__ Wx,
    f16* __restrict__ G)
{
  const int lane = threadIdx.x & 63, w = threadIdx.x >> 6;
  const int lo = lane & 15, quad = lane >> 4;
  const int m0 = blockIdx.x * 128 + (w >> 1) * 64;
  const int n0 = blockIdx.y * 128 + (w & 1) * 64;
  f32x4 acc[4][4] = {};
  #pragma unroll 2
  for (int k0 = 0; k0 < F_; k0 += 32) {
    bf16x8 a[4], b[4];
    #pragma unroll
    for (int mt = 0; mt < 4; mt++)
      a[mt] = *(const bf16x8*)(X + (size_t)(m0 + 16*mt + lo) * F_ + k0 + quad*8);
    #pragma unroll
    for (int nt = 0; nt < 4; nt++)
      b[nt] = *(const bf16x8*)(Wx + (size_t)(n0 + 16*nt + lo) * F_ + k0 + quad*8);
    #pragma unroll
    for (int mt = 0; mt < 4; mt++)
      #pragma unroll
      for (int nt = 0; nt < 4; nt++)
        acc[mt][nt] = __builtin_amdgcn_mfma_f32_16x16x32_bf16(a[mt], b[nt], acc[mt][nt], 0, 0, 0);
  }
  #pragma unroll
  for (int mt = 0; mt < 4; mt++)
    #pragma unroll
    for (int nt = 0; nt < 4; nt++)
      #pragma unroll
      for (int r = 0; r < 4; r++) {
        int row = m0 + 16*mt + quad*4 + r;
        int col = n0 + 16*nt + lo;
        G[(size_t)row * NG_ + col] = (f16)acc[mt][nt][r];
      }
}

// device-scope sense counter grid barrier
__device__ __forceinline__ void gbar(int* bar, int target){
  __syncthreads();
  if (threadIdx.x == 0){
    __hip_atomic_fetch_add(bar, 1, __ATOMIC_RELEASE, __HIP_MEMORY_SCOPE_AGENT);
    while (__hip_atomic_load(bar, __ATOMIC_ACQUIRE, __HIP_MEMORY_SCOPE_AGENT) < target)
      __builtin_amdgcn_s_sleep(2);
  }
  __syncthreads();
}

// Persistent cooperative recurrence for 16 steps.
// 256 blocks = 32 colgroups x 4 gates x 2 batch-halves; 256 thr = 4 waves
// = (K-half wkh) x (N-half wnt). U-slice (32 rows x 1024 K, 64 KB) in LDS.
// Partial preacts (f16) exchanged via global Pre[2][4][64][1024]; cell state
// in registers (1 elem/thread) across all 16 steps.
__global__ __launch_bounds__(256) void recur_coop(
    const f16* __restrict__ U, const f16* __restrict__ Gc,
    const float* __restrict__ bias, f16* __restrict__ Ht,
    float* __restrict__ Cst, f16* __restrict__ Pre, int* __restrict__ bar)
{
  __shared__ f16 Usm[32768];  // 64 KB, frag-ordered: frag f=(nt*32+kglob), 512 f16
  const int blk = blockIdx.x;
  const int cg = blk & 31, rest = blk >> 5;
  const int g = rest & 3, mh = rest >> 2;
  const int tid = threadIdx.x;
  const int lane = tid & 63, w = tid >> 6;
  const int lo = lane & 15, quad = lane >> 4;
  const int wnt = w & 1, wkh = w >> 1;

  // stage U rows [g*1024 + cg*32, +32) into LDS, frag-ordered (once per launch)
  #pragma unroll
  for (int ff = 0; ff < 16; ff++) {
    int f = w*16 + ff;
    int nt = f >> 5, kg = f & 31;
    int row = g*1024 + cg*32 + nt*16 + lo;
    *(f16x8*)(Usm + f*512 + lane*8) =
        *(const f16x8*)(U + (size_t)row*H_ + kg*32 + quad*8);
  }
  // elementwise ownership: batch row eb, col ecol (1 elem/thread)
  const int eb = rest*8 + (tid >> 5);
  const int ecol = cg*32 + (tid & 31);
  float creg = Cst[(size_t)eb*H_ + ecol];
  __syncthreads();

  const int colw = cg*32 + wnt*16 + lo;     // preact write col
  for (int s = 0; s < CHUNK_; s++) {
    const f16* Hp = Ht + (size_t)s*B_*H_;
    const f16* arow0 = Hp + (size_t)(mh*32 + lo)*H_ + wkh*512;
    const f16* arow1 = arow0 + (size_t)16*H_;
    f32x4 acc0 = {0.f,0.f,0.f,0.f}, acc1 = {0.f,0.f,0.f,0.f};
    #pragma unroll 4
    for (int ki = 0; ki < 16; ki++) {
      f16x8 bfr = *(const f16x8*)(Usm + (wnt*32 + wkh*16 + ki)*512 + lane*8);
      f16x8 a0 = *(const f16x8*)(arow0 + ki*32 + quad*8);
      f16x8 a1 = *(const f16x8*)(arow1 + ki*32 + quad*8);
      acc0 = __builtin_amdgcn_mfma_f32_16x16x32_f16(a0, bfr, acc0, 0, 0, 0);
      acc1 = __builtin_amdgcn_mfma_f32_16x16x32_f16(a1, bfr, acc1, 0, 0, 0);
    }
    {
      f16* pp = Pre + (size_t)(wkh*4 + g)*65536 + (size_t)(mh*32 + quad*4)*1024 + colw;
      #pragma unroll
      for (int r = 0; r < 4; r++) {
        pp[(size_t)r*1024]        = (f16)acc0[r];
        pp[(size_t)(16+r)*1024]   = (f16)acc1[r];
      }
    }
    gbar(bar, (2*s+1)*NBLK_R);
    {
      size_t pb = (size_t)eb*1024 + ecol;
      const f16* gg = Gc + ((size_t)s*B_ + eb)*NG_ + ecol;
      float pf = (float)Pre[pb]             + (float)Pre[4*65536 + pb] + (float)gg[0]    + bias[ecol];
      float pi = (float)Pre[1*65536 + pb]   + (float)Pre[5*65536 + pb] + (float)gg[1024] + bias[1024+ecol];
      float po = (float)Pre[2*65536 + pb]   + (float)Pre[6*65536 + pb] + (float)gg[2048] + bias[2048+ecol];
      float pa = (float)Pre[3*65536 + pb]   + (float)Pre[7*65536 + pb] + (float)gg[3072] + bias[3072+ecol];
      float vf = sigm(pf), vi = sigm(pi), vo = sigm(po);
      creg = vi * tanh_(pa) + vf * creg;
      float hn = vo * tanh_(creg);
      Ht[(size_t)(s+1)*B_*H_ + (size_t)eb*H_ + ecol] = (f16)hn;
    }
    gbar(bar, (2*s+2)*NBLK_R);
  }
  Cst[(size_t)eb*H_ + ecol] = creg;
}

// out = Hall[1..128] @ Fco^T-layout + ob : M=8192, N=640(pad), K=1024, fp32 out
__global__ __launch_bounds__(256) void gemm_out(
    const f16* __restrict__ A,
    const f16* __restrict__ Bt,
    const float* __restrict__ ob,
    float* __restrict__ out)
{
  const int lane = threadIdx.x & 63, w = threadIdx.x >> 6;
  const int lo = lane & 15, quad = lane >> 4;
  const int m0 = blockIdx.x * 128 + (w >> 1) * 64;
  const int n0 = blockIdx.y * 128 + (w & 1) * 64;
  f32x4 acc[4][4] = {};
  #pragma unroll 2
  for (int k0 = 0; k0 < H_; k0 += 32) {
    f16x8 a[4], b[4];
    #pragma unroll
    for (int mt = 0; mt < 4; mt++)
      a[mt] = *(const f16x8*)(A + (size_t)(m0 + 16*mt + lo) * H_ + k0 + quad*8);
    #pragma unroll
    for (int nt = 0; nt < 4; nt++)
      b[nt] = *(const f16x8*)(Bt + (size_t)(n0 + 16*nt + lo) * H_ + k0 + quad*8);
    #pragma unroll
    for (int mt = 0; mt < 4; mt++)
      #pragma unroll
      for (int nt = 0; nt < 4; nt++)
        acc[mt][nt] = __builtin_amdgcn_mfma_f32_16x16x32_f16(a[mt], b[nt], acc[mt][nt], 0, 0, 0);
  }
  #pragma unroll
  for (int mt = 0; mt < 4; mt++)
    #pragma unroll
    for (int nt = 0; nt < 4; nt++)
      #pragma unroll
      for (int r = 0; r < 4; r++) {
        int row = m0 + 16*mt + quad*4 + r;
        int col = n0 + 16*nt + lo;
        if (col < NO_)
          out[(size_t)row * NO_ + col] = acc[mt][nt][r] + ob[col];
      }
}

extern "C" void kernel_launch(void* const* d_in, const int* in_sizes, int n_in,
                              void* d_out, int out_size, void* d_ws, size_t ws_size,
                              hipStream_t stream)
{
  const void* x   = d_in[0];
  const void* wfw = d_in[1];  const void* wfb = d_in[2];
  const void* wiw = d_in[3];  const void* wib = d_in[4];
  const void* wow = d_in[5];  const void* wob = d_in[6];
  const void* wcw = d_in[7];  const void* wcb = d_in[8];
  const void* ufw = d_in[9];  const void* uiw = d_in[10];
  const void* uow = d_in[11]; const void* ucw = d_in[12];
  const void* fcw = d_in[13]; const void* fcb = d_in[14];

  char* ws = (char*)d_ws;
  unsigned short* Wx = (unsigned short*)(ws + 0);        //  4,194,304 B
  f16*   U    = (f16*)  (ws + 4194304);                  //  8,388,608 B
  f16*   Fco  = (f16*)  (ws + 12582912);                 //  1,310,720 B
  f16*   G    = (f16*)  (ws + 13893632);                 //  8,388,608 B
  f16*   Hall = (f16*)  (ws + 22282240);                 // 16,908,288 B (129 states)
  float* C    = (float*)(ws + 39190528);                 //    262,144 B
  float* bias = (float*)(ws + 39452672);                 //     16,384 B
  float* ob   = (float*)(ws + 39469056);                 //      2,560 B
  // Xc (1 MB, used convert->gemm_g) and Pre (1 MB, used in recur_coop)
  // time-share the same region within each chunk.
  unsigned short* Xc = (unsigned short*)(ws + 39471616); //  1,048,576 B
  f16*   Pre  = (f16*) (ws + 39471616);                  //  (overlay)
  int*   flag = (int*)  (ws + 40520192);                 //  4 B
  int*   bar  = (int*)  (ws + 40520200);                 //  4 B
  if (ws_size < 40520208u) return;

  hipMemsetAsync(Hall, 0, (size_t)B_*H_*sizeof(f16), stream);  // h_{-1} = 0
  hipMemsetAsync(C, 0, (size_t)B_*H_*sizeof(float), stream);   // c_{-1} = 0

  detect_kernel<<<1, 256, 0, stream>>>((const unsigned short*)x, flag);

  pack_kernel<<<(PACK_TOTAL + 255)/256, 256, 0, stream>>>(
      wfw, wiw, wow, wcw, wfb, wib, wob, wcb, ufw, uiw, uow, ucw, fcw, fcb,
      flag, Wx, U, Fco, bias, ob);

  for (int c = 0; c < T_/CHUNK_; c++) {
    convert_x<<<512, 256, 0, stream>>>(x, c * XCHUNK_ELEMS, flag, Xc);
    gemm_g<<<dim3(8, 32), 256, 0, stream>>>(Xc, Wx, G);
    hipMemsetAsync(bar, 0, sizeof(int), stream);
    {
      const f16* Up = U;
      const f16* Gp = G;
      const float* bp = bias;
      f16* Htp = Hall + (size_t)c*CHUNK_*B_*H_;
      float* Cp = C;
      f16* Pp = Pre;
      int* barp = bar;
      void* args[] = {&Up, &Gp, &bp, &Htp, &Cp, &Pp, &barp};
      hipLaunchCooperativeKernel((const void*)recur_coop, dim3(NBLK_R), dim3(256),
                                 args, 0, stream);
    }
  }
  gemm_out<<<dim3(64, 5), 256, 0, stream>>>(Hall + (size_t)B_*H_, Fco, ob, (float*)d_out);
}

// Round 5
// 1600.837 us; speedup vs baseline: 2.3887x; 2.3887x over previous
//
#include <hip/hip_runtime.h>
#include <stdint.h>

typedef _Float16 f16;
typedef _Float16 f16x8 __attribute__((ext_vector_type(8)));
typedef short bf16x8 __attribute__((ext_vector_type(8)));
typedef float f32x4 __attribute__((ext_vector_type(4)));

#define H_ 1024
#define NG_ 4096
#define F_ 512
#define B_ 64
#define T_ 128
#define CHUNK_ 16
#define NOP_ 640
#define NO_ 513
#define NBLK_R 128

// Hamilton block structure: W[p-block(in)][q-block(out)] = sign * comp
__constant__ int c_comp[16] = {0,1,2,3, 1,0,3,2, 2,3,0,1, 3,2,1,0};
__constant__ float c_sgnf[16] = {1,1,1,1, -1,1,1,-1, -1,-1,1,1, -1,1,-1,1};

__device__ __forceinline__ float bf2f(unsigned short u){
  union { unsigned int i; float f; } v; v.i = ((unsigned int)u) << 16; return v.f;
}
__device__ __forceinline__ unsigned short f2bf(float f){
  union { float f; unsigned int i; } v; v.f = f;
  return (unsigned short)((v.i + 0x7fffu + ((v.i >> 16) & 1u)) >> 16);
}
__device__ __forceinline__ float ldin(const void* p, int i, int f){
  return f ? ((const float*)p)[i] : bf2f(((const unsigned short*)p)[i]);
}
__device__ __forceinline__ float sigm(float x){ return 1.f / (1.f + __expf(-x)); }
__device__ __forceinline__ float tanh_(float x){
  float ax = fabsf(x);
  float e = __expf(-2.f * ax);
  float t = (1.f - e) / (1.f + e);
  return x < 0.f ? -t : t;
}

// ---- system-coherent (IF$-level) memory ops: bypass L1/L2, no fences needed ----
__device__ __forceinline__ void load_a8_sys(const f16* p, f16x8* a){
  asm volatile(
    "global_load_dwordx4 %0, %8, off sc0 sc1\n\t"
    "global_load_dwordx4 %1, %8, off offset:64 sc0 sc1\n\t"
    "global_load_dwordx4 %2, %8, off offset:128 sc0 sc1\n\t"
    "global_load_dwordx4 %3, %8, off offset:192 sc0 sc1\n\t"
    "global_load_dwordx4 %4, %8, off offset:256 sc0 sc1\n\t"
    "global_load_dwordx4 %5, %8, off offset:320 sc0 sc1\n\t"
    "global_load_dwordx4 %6, %8, off offset:384 sc0 sc1\n\t"
    "global_load_dwordx4 %7, %8, off offset:448 sc0 sc1\n\t"
    "s_waitcnt vmcnt(0)"
    : "=v"(a[0]),"=v"(a[1]),"=v"(a[2]),"=v"(a[3]),
      "=v"(a[4]),"=v"(a[5]),"=v"(a[6]),"=v"(a[7])
    : "v"(p) : "memory");
}
__device__ __forceinline__ void store_h_sys(f16* p, f16 v){
  asm volatile("global_store_short %0, %1, off sc0 sc1" :: "v"(p), "v"(v) : "memory");
}
__device__ __forceinline__ void drain_vmem(){
  asm volatile("s_waitcnt vmcnt(0)" ::: "memory");
}

__global__ void detect_kernel(const unsigned short* __restrict__ xu, int* __restrict__ flag){
  __shared__ int zc, wc;
  if (threadIdx.x == 0){ zc = 0; wc = 0; }
  __syncthreads();
  unsigned short u = xu[2 * threadIdx.x];
  int e = (u >> 7) & 0xFF;
  bool z = (u & 0x7FFF) == 0;
  bool wild = !z && (e < 67 || e > 150);
  if (z) atomicAdd(&zc, 1);
  if (wild) atomicAdd(&wc, 1);
  __syncthreads();
  if (threadIdx.x == 0) *flag = (zc >= 128 || wc >= 64) ? 1 : 0;
}

#define XCHUNK_ELEMS (CHUNK_*B_*F_)   // 524288
__global__ void convert_x(const void* __restrict__ x, int elem_off,
                          const int* __restrict__ flag,
                          unsigned short* __restrict__ Xc){
  int f = *flag;
  int i = blockIdx.x * blockDim.x + threadIdx.x;
  int stride = gridDim.x * blockDim.x;
  for (; i < XCHUNK_ELEMS; i += stride) {
    int si = elem_off + i;
    Xc[i] = f ? f2bf(((const float*)x)[si]) : ((const unsigned short*)x)[si];
  }
}

#define WX_ELEMS (NG_*F_)
#define U_ELEMS  (NG_*H_)
#define FCO_ELEMS (NOP_*H_)
#define BIAS_ELEMS NG_
#define OB_ELEMS NOP_
#define PACK_TOTAL (WX_ELEMS + U_ELEMS + FCO_ELEMS + BIAS_ELEMS + OB_ELEMS)

__global__ void pack_kernel(
    const void* __restrict__ wf, const void* __restrict__ wi,
    const void* __restrict__ wo, const void* __restrict__ wc,
    const void* __restrict__ bfv, const void* __restrict__ biv,
    const void* __restrict__ bov, const void* __restrict__ bcv,
    const void* __restrict__ uf, const void* __restrict__ ui,
    const void* __restrict__ uo, const void* __restrict__ uc,
    const void* __restrict__ fcw, const void* __restrict__ fcb,
    const int* __restrict__ flag,
    unsigned short* __restrict__ Wx, f16* __restrict__ U, f16* __restrict__ Fco,
    float* __restrict__ bias, float* __restrict__ ob)
{
  const int fl = *flag;
  int i = blockIdx.x * blockDim.x + threadIdx.x;
  if (i < WX_ELEMS) {
    int n = i >> 9, k = i & 511;
    int g = n >> 10, nn = n & 1023;
    int q = nn >> 8, be = nn & 255;
    int p = k >> 7, al = k & 127;
    const void* w = (g==0) ? wf : (g==1) ? wi : (g==2) ? wo : wc;
    int pq = p*4 + q;
    Wx[i] = f2bf(c_sgnf[pq] * ldin(w, c_comp[pq]*32768 + al*256 + be, fl));
    return;
  }
  i -= WX_ELEMS;
  if (i < U_ELEMS) {
    int n = i >> 10, k = i & 1023;
    int g = n >> 10;
    int q = (n & 1023) >> 8, be = n & 255;
    int p = k >> 8, al = k & 255;
    const void* u = (g==0) ? uf : (g==1) ? ui : (g==2) ? uo : uc;
    int pq = p*4 + q;
    U[i] = (f16)(c_sgnf[pq] * ldin(u, c_comp[pq]*65536 + al*256 + be, fl));
    return;
  }
  i -= U_ELEMS;
  if (i < FCO_ELEMS) {
    int n = i >> 10, k = i & 1023;
    Fco[i] = (n < NO_) ? (f16)ldin(fcw, k*NO_ + n, fl) : (f16)0.f;
    return;
  }
  i -= FCO_ELEMS;
  if (i < BIAS_ELEMS) {
    int g = i >> 10;
    const void* b = (g==0) ? bfv : (g==1) ? biv : (g==2) ? bov : bcv;
    bias[i] = ldin(b, i & 1023, fl);
    return;
  }
  i -= BIAS_ELEMS;
  if (i < OB_ELEMS) {
    ob[i] = (i < NO_) ? ldin(fcb, i, fl) : 0.f;
  }
}

// G = Xc @ Wx^T-layout + bias : M=1024, N=4096, K=512, bf16 MFMA, f16 store
__global__ __launch_bounds__(256) void gemm_g(
    const unsigned short* __restrict__ X,
    const unsigned short* __restrict__ Wx,
    const float* __restrict__ bias,
    f16* __restrict__ G)
{
  const int lane = threadIdx.x & 63, w = threadIdx.x >> 6;
  const int lo = lane & 15, quad = lane >> 4;
  const int m0 = blockIdx.x * 128 + (w >> 1) * 64;
  const int n0 = blockIdx.y * 128 + (w & 1) * 64;
  f32x4 acc[4][4] = {};
  #pragma unroll 2
  for (int k0 = 0; k0 < F_; k0 += 32) {
    bf16x8 a[4], b[4];
    #pragma unroll
    for (int mt = 0; mt < 4; mt++)
      a[mt] = *(const bf16x8*)(X + (size_t)(m0 + 16*mt + lo) * F_ + k0 + quad*8);
    #pragma unroll
    for (int nt = 0; nt < 4; nt++)
      b[nt] = *(const bf16x8*)(Wx + (size_t)(n0 + 16*nt + lo) * F_ + k0 + quad*8);
    #pragma unroll
    for (int mt = 0; mt < 4; mt++)
      #pragma unroll
      for (int nt = 0; nt < 4; nt++)
        acc[mt][nt] = __builtin_amdgcn_mfma_f32_16x16x32_bf16(a[mt], b[nt], acc[mt][nt], 0, 0, 0);
  }
  #pragma unroll
  for (int mt = 0; mt < 4; mt++)
    #pragma unroll
    for (int nt = 0; nt < 4; nt++)
      #pragma unroll
      for (int r = 0; r < 4; r++) {
        int row = m0 + 16*mt + quad*4 + r;
        int col = n0 + 16*nt + lo;
        G[(size_t)row * NG_ + col] = (f16)(acc[mt][nt][r] + bias[col]);
      }
}

// Persistent cooperative recurrence for one 16-step chunk.
// 128 blocks x 256 thr (4 waves). Block owns cols jb..jb+8 for ALL 4 gates:
// U-slice 32 rows x 1024 K = 64 KB LDS (frag-ordered). Wave w = m-tile
// (batches w*16..+16), computes N=32 (2 n-tiles: gates 0-1, 2-3), K=1024.
// Gate-combine is intra-wave via shuffles (C-layout: col=lane&15, row=quad*4+r).
// Cross-block h exchange: sc0/sc1 (IF$-coherent) stores+loads, fence-free
// relaxed-atomic barrier (1 per step). Cell state in registers (2/thread).
__global__ __launch_bounds__(256) void recur_coop(
    const f16* __restrict__ U, const f16* __restrict__ Gc,
    f16* __restrict__ Ht, float* __restrict__ Cst, int* __restrict__ bar)
{
  __shared__ f16 Usm[32768];  // 64 KB: frag f = ki*2+nt (64), 512 f16 each
  const int blk = blockIdx.x;
  const int jb = blk * 8;
  const int tid = threadIdx.x;
  const int lane = tid & 63, w = tid >> 6;
  const int lo = lane & 15, quad = lane >> 4;
  const int m0 = w * 16;

  // stage U-slice into LDS, frag-ordered (once per launch)
  #pragma unroll
  for (int j = 0; j < 16; j++) {
    int u = tid + j*256;              // 4096 16B-units
    int lp = u & 63, f = u >> 6;
    int ki = f >> 1, nt = f & 1;
    int n = nt*16 + (lp & 15), qd = lp >> 4;
    int row = (n >> 3)*H_ + jb + (n & 7);
    *(f16x8*)(Usm + f*512 + lp*8) =
        *(const f16x8*)(U + (size_t)row*H_ + ki*32 + qd*8);
  }
  // elementwise ownership: lane(q=quad, i=lane&15): c=i&7, hi=i>>3,
  // rows b_e = m0 + q*4 + hi*2 + e  (e=0,1), col = jb + c
  const int c = lane & 7, hi = (lane >> 3) & 1;
  const int colg = jb + c;
  const int b0r = m0 + quad*4 + hi*2;
  float creg[2];
  creg[0] = Cst[(size_t)b0r*H_ + colg];
  creg[1] = Cst[(size_t)(b0r+1)*H_ + colg];
  __syncthreads();

  for (int s = 0; s < CHUNK_; s++) {
    // prefetch G preacts (bias already folded in) - normal cached loads
    float gv[2][4];
    {
      const f16* gg0 = Gc + ((size_t)(s*B_ + b0r))*NG_ + colg;
      const f16* gg1 = gg0 + NG_;
      #pragma unroll
      for (int g = 0; g < 4; g++) {
        gv[0][g] = (float)gg0[g*1024];
        gv[1][g] = (float)gg1[g*1024];
      }
    }
    // K-loop: A from h[t] via IF$-coherent batched loads, B from LDS
    const f16* Ap = Ht + (size_t)s*B_*H_ + (size_t)(m0 + lo)*H_ + quad*8;
    f32x4 acc0 = {0.f,0.f,0.f,0.f}, acc1 = {0.f,0.f,0.f,0.f};
    #pragma unroll
    for (int kb = 0; kb < 4; kb++) {
      f16x8 a[8];
      load_a8_sys(Ap + kb*256, a);
      #pragma unroll
      for (int u = 0; u < 8; u++) {
        int ki = kb*8 + u;
        f16x8 bb0 = *(const f16x8*)(Usm + (ki*2+0)*512 + lane*8);
        f16x8 bb1 = *(const f16x8*)(Usm + (ki*2+1)*512 + lane*8);
        acc0 = __builtin_amdgcn_mfma_f32_16x16x32_f16(a[u], bb0, acc0, 0, 0, 0);
        acc1 = __builtin_amdgcn_mfma_f32_16x16x32_f16(a[u], bb1, acc1, 0, 0, 0);
      }
    }
    // gate-combine in-wave: value for (row=q*4+hi*2+e, gate g) lives at
    // lane q*16 + (g&1)*8 + c, acc[g>>1], reg hi*2+e
    f16* Hn = Ht + (size_t)(s+1)*B_*H_;
    #pragma unroll
    for (int e = 0; e < 2; e++) {
      int src = quad*16 + c;
      float f_lo = __shfl(acc0[e],     src);      // g0, reg e   (if hi=0)
      float f_hi = __shfl(acc0[2+e],   src);      // g0, reg 2+e (if hi=1)
      float i_lo = __shfl(acc0[e],     src + 8);  // g1
      float i_hi = __shfl(acc0[2+e],   src + 8);
      float o_lo = __shfl(acc1[e],     src);      // g2
      float o_hi = __shfl(acc1[2+e],   src);
      float a_lo = __shfl(acc1[e],     src + 8);  // g3
      float a_hi = __shfl(acc1[2+e],   src + 8);
      float pf = (hi ? f_hi : f_lo) + gv[e][0];
      float pi = (hi ? i_hi : i_lo) + gv[e][1];
      float po = (hi ? o_hi : o_lo) + gv[e][2];
      float pa = (hi ? a_hi : a_lo) + gv[e][3];
      float vf = sigm(pf), vi = sigm(pi), vo = sigm(po);
      creg[e] = vi * tanh_(pa) + vf * creg[e];
      float hn = vo * tanh_(creg[e]);
      store_h_sys(Hn + (size_t)(b0r + e)*H_ + colg, (f16)hn);
    }
    drain_vmem();            // h writes acked at IF$ (coherence point)
    __syncthreads();
    if (tid == 0) {
      __hip_atomic_fetch_add(bar, 1, __ATOMIC_RELAXED, __HIP_MEMORY_SCOPE_AGENT);
      int target = (s+1) * NBLK_R;
      while (__hip_atomic_load(bar, __ATOMIC_RELAXED, __HIP_MEMORY_SCOPE_AGENT) < target)
        __builtin_amdgcn_s_sleep(1);
    }
    __syncthreads();
  }
  Cst[(size_t)b0r*H_ + colg]     = creg[0];
  Cst[(size_t)(b0r+1)*H_ + colg] = creg[1];
}

// out = Hall[1..128] @ Fco^T-layout + ob : M=8192, N=640(pad), K=1024, fp32 out
__global__ __launch_bounds__(256) void gemm_out(
    const f16* __restrict__ A,
    const f16* __restrict__ Bt,
    const float* __restrict__ ob,
    float* __restrict__ out)
{
  const int lane = threadIdx.x & 63, w = threadIdx.x >> 6;
  const int lo = lane & 15, quad = lane >> 4;
  const int m0 = blockIdx.x * 128 + (w >> 1) * 64;
  const int n0 = blockIdx.y * 128 + (w & 1) * 64;
  f32x4 acc[4][4] = {};
  #pragma unroll 2
  for (int k0 = 0; k0 < H_; k0 += 32) {
    f16x8 a[4], b[4];
    #pragma unroll
    for (int mt = 0; mt < 4; mt++)
      a[mt] = *(const f16x8*)(A + (size_t)(m0 + 16*mt + lo) * H_ + k0 + quad*8);
    #pragma unroll
    for (int nt = 0; nt < 4; nt++)
      b[nt] = *(const f16x8*)(Bt + (size_t)(n0 + 16*nt + lo) * H_ + k0 + quad*8);
    #pragma unroll
    for (int mt = 0; mt < 4; mt++)
      #pragma unroll
      for (int nt = 0; nt < 4; nt++)
        acc[mt][nt] = __builtin_amdgcn_mfma_f32_16x16x32_f16(a[mt], b[nt], acc[mt][nt], 0, 0, 0);
  }
  #pragma unroll
  for (int mt = 0; mt < 4; mt++)
    #pragma unroll
    for (int nt = 0; nt < 4; nt++)
      #pragma unroll
      for (int r = 0; r < 4; r++) {
        int row = m0 + 16*mt + quad*4 + r;
        int col = n0 + 16*nt + lo;
        if (col < NO_)
          out[(size_t)row * NO_ + col] = acc[mt][nt][r] + ob[col];
      }
}

extern "C" void kernel_launch(void* const* d_in, const int* in_sizes, int n_in,
                              void* d_out, int out_size, void* d_ws, size_t ws_size,
                              hipStream_t stream)
{
  const void* x   = d_in[0];
  const void* wfw = d_in[1];  const void* wfb = d_in[2];
  const void* wiw = d_in[3];  const void* wib = d_in[4];
  const void* wow = d_in[5];  const void* wob = d_in[6];
  const void* wcw = d_in[7];  const void* wcb = d_in[8];
  const void* ufw = d_in[9];  const void* uiw = d_in[10];
  const void* uow = d_in[11]; const void* ucw = d_in[12];
  const void* fcw = d_in[13]; const void* fcb = d_in[14];

  char* ws = (char*)d_ws;
  unsigned short* Wx = (unsigned short*)(ws + 0);        //  4,194,304 B
  f16*   U    = (f16*)  (ws + 4194304);                  //  8,388,608 B
  f16*   Fco  = (f16*)  (ws + 12582912);                 //  1,310,720 B
  f16*   G    = (f16*)  (ws + 13893632);                 //  8,388,608 B
  f16*   Hall = (f16*)  (ws + 22282240);                 // 16,908,288 B (129 states)
  float* C    = (float*)(ws + 39190528);                 //    262,144 B
  float* bias = (float*)(ws + 39452672);                 //     16,384 B
  float* ob   = (float*)(ws + 39469056);                 //      2,560 B
  unsigned short* Xc = (unsigned short*)(ws + 39471616); //  1,048,576 B
  int*   flag = (int*)  (ws + 40520192);                 //  4 B
  int*   bar  = (int*)  (ws + 40520200);                 //  4 B
  if (ws_size < 40520208u) return;

  hipMemsetAsync(Hall, 0, (size_t)B_*H_*sizeof(f16), stream);  // h_{-1} = 0
  hipMemsetAsync(C, 0, (size_t)B_*H_*sizeof(float), stream);   // c_{-1} = 0

  detect_kernel<<<1, 256, 0, stream>>>((const unsigned short*)x, flag);

  pack_kernel<<<(PACK_TOTAL + 255)/256, 256, 0, stream>>>(
      wfw, wiw, wow, wcw, wfb, wib, wob, wcb, ufw, uiw, uow, ucw, fcw, fcb,
      flag, Wx, U, Fco, bias, ob);

  for (int c = 0; c < T_/CHUNK_; c++) {
    convert_x<<<512, 256, 0, stream>>>(x, c * XCHUNK_ELEMS, flag, Xc);
    gemm_g<<<dim3(8, 32), 256, 0, stream>>>(Xc, Wx, bias, G);
    hipMemsetAsync(bar, 0, sizeof(int), stream);
    {
      const f16* Up = U;
      const f16* Gp = G;
      f16* Htp = Hall + (size_t)c*CHUNK_*B_*H_;
      float* Cp = C;
      int* barp = bar;
      void* args[] = {&Up, &Gp, &Htp, &Cp, &barp};
      hipLaunchCooperativeKernel((const void*)recur_coop, dim3(NBLK_R), dim3(256),
                                 args, 0, stream);
    }
  }
  gemm_out<<<dim3(64, 5), 256, 0, stream>>>(Hall + (size_t)B_*H_, Fco, ob, (float*)d_out);
}

// Round 6
// 1440.434 us; speedup vs baseline: 2.6547x; 1.1114x over previous
//
#include <hip/hip_runtime.h>
#include <stdint.h>

typedef _Float16 f16;
typedef _Float16 f16x8 __attribute__((ext_vector_type(8)));
typedef short bf16x8 __attribute__((ext_vector_type(8)));
typedef float f32x4 __attribute__((ext_vector_type(4)));

#define H_ 1024
#define NG_ 4096
#define F_ 512
#define B_ 64
#define T_ 128
#define CHUNK_ 16
#define NOP_ 640
#define NO_ 513
#define NBLK_R 128

// Hamilton block structure: W[p-block(in)][q-block(out)] = sign * comp
__constant__ int c_comp[16] = {0,1,2,3, 1,0,3,2, 2,3,0,1, 3,2,1,0};
__constant__ float c_sgnf[16] = {1,1,1,1, -1,1,1,-1, -1,-1,1,1, -1,1,-1,1};

__device__ __forceinline__ float bf2f(unsigned short u){
  union { unsigned int i; float f; } v; v.i = ((unsigned int)u) << 16; return v.f;
}
__device__ __forceinline__ unsigned short f2bf(float f){
  union { float f; unsigned int i; } v; v.f = f;
  return (unsigned short)((v.i + 0x7fffu + ((v.i >> 16) & 1u)) >> 16);
}
__device__ __forceinline__ float ldin(const void* p, int i, int f){
  return f ? ((const float*)p)[i] : bf2f(((const unsigned short*)p)[i]);
}
__device__ __forceinline__ float sigm(float x){ return 1.f / (1.f + __expf(-x)); }
__device__ __forceinline__ float tanh_(float x){
  float ax = fabsf(x);
  float e = __expf(-2.f * ax);
  float t = (1.f - e) / (1.f + e);
  return x < 0.f ? -t : t;
}

// ---- system-coherent (IF$-level) memory ops: bypass L1/L2, no fences ----
__device__ __forceinline__ void load_a8_nw(const f16* p, f16x8* a){
  asm volatile(
    "global_load_dwordx4 %0, %8, off sc0 sc1\n\t"
    "global_load_dwordx4 %1, %8, off offset:64 sc0 sc1\n\t"
    "global_load_dwordx4 %2, %8, off offset:128 sc0 sc1\n\t"
    "global_load_dwordx4 %3, %8, off offset:192 sc0 sc1\n\t"
    "global_load_dwordx4 %4, %8, off offset:256 sc0 sc1\n\t"
    "global_load_dwordx4 %5, %8, off offset:320 sc0 sc1\n\t"
    "global_load_dwordx4 %6, %8, off offset:384 sc0 sc1\n\t"
    "global_load_dwordx4 %7, %8, off offset:448 sc0 sc1"
    : "=v"(a[0]),"=v"(a[1]),"=v"(a[2]),"=v"(a[3]),
      "=v"(a[4]),"=v"(a[5]),"=v"(a[6]),"=v"(a[7])
    : "v"(p) : "memory");
}
__device__ __forceinline__ void store_h_sys(f16* p, f16 v){
  asm volatile("global_store_short %0, %1, off sc0 sc1" :: "v"(p), "v"(v) : "memory");
}
__device__ __forceinline__ void store_flag_sys(int* p, int v){
  asm volatile("global_store_dword %0, %1, off sc0 sc1" :: "v"(p), "v"(v) : "memory");
}
__device__ __forceinline__ void load_flag2_sys(const int* p0, const int* p1, int &a, int &b){
  asm volatile(
    "global_load_dword %0, %2, off sc0 sc1\n\t"
    "global_load_dword %1, %3, off sc0 sc1\n\t"
    "s_waitcnt vmcnt(0)"
    : "=v"(a), "=v"(b) : "v"(p0), "v"(p1) : "memory");
}
__device__ __forceinline__ void drain_vmem(){
  asm volatile("s_waitcnt vmcnt(0)" ::: "memory");
}
#define WAIT_VM(n) asm volatile("s_waitcnt vmcnt(" #n ")" ::: "memory")

__global__ void detect_kernel(const unsigned short* __restrict__ xu, int* __restrict__ flag){
  __shared__ int zc, wc;
  if (threadIdx.x == 0){ zc = 0; wc = 0; }
  __syncthreads();
  unsigned short u = xu[2 * threadIdx.x];
  int e = (u >> 7) & 0xFF;
  bool z = (u & 0x7FFF) == 0;
  bool wild = !z && (e < 67 || e > 150);
  if (z) atomicAdd(&zc, 1);
  if (wild) atomicAdd(&wc, 1);
  __syncthreads();
  if (threadIdx.x == 0) *flag = (zc >= 128 || wc >= 64) ? 1 : 0;
}

#define WX_ELEMS (NG_*F_)
#define U_ELEMS  (NG_*H_)
#define FCO_ELEMS (NOP_*H_)
#define BIAS_ELEMS NG_
#define OB_ELEMS NOP_
#define PACK_TOTAL (WX_ELEMS + U_ELEMS + FCO_ELEMS + BIAS_ELEMS + OB_ELEMS)

__global__ void pack_kernel(
    const void* __restrict__ wf, const void* __restrict__ wi,
    const void* __restrict__ wo, const void* __restrict__ wc,
    const void* __restrict__ bfv, const void* __restrict__ biv,
    const void* __restrict__ bov, const void* __restrict__ bcv,
    const void* __restrict__ uf, const void* __restrict__ ui,
    const void* __restrict__ uo, const void* __restrict__ uc,
    const void* __restrict__ fcw, const void* __restrict__ fcb,
    const int* __restrict__ flag,
    unsigned short* __restrict__ Wx, f16* __restrict__ U, f16* __restrict__ Fco,
    float* __restrict__ bias, float* __restrict__ ob)
{
  const int fl = *flag;
  int i = blockIdx.x * blockDim.x + threadIdx.x;
  if (i < WX_ELEMS) {
    int n = i >> 9, k = i & 511;
    int g = n >> 10, nn = n & 1023;
    int q = nn >> 8, be = nn & 255;
    int p = k >> 7, al = k & 127;
    const void* w = (g==0) ? wf : (g==1) ? wi : (g==2) ? wo : wc;
    int pq = p*4 + q;
    Wx[i] = f2bf(c_sgnf[pq] * ldin(w, c_comp[pq]*32768 + al*256 + be, fl));
    return;
  }
  i -= WX_ELEMS;
  if (i < U_ELEMS) {
    int n = i >> 10, k = i & 1023;
    int g = n >> 10;
    int q = (n & 1023) >> 8, be = n & 255;
    int p = k >> 8, al = k & 255;
    const void* u = (g==0) ? uf : (g==1) ? ui : (g==2) ? uo : uc;
    int pq = p*4 + q;
    U[i] = (f16)(c_sgnf[pq] * ldin(u, c_comp[pq]*65536 + al*256 + be, fl));
    return;
  }
  i -= U_ELEMS;
  if (i < FCO_ELEMS) {
    int n = i >> 10, k = i & 1023;
    Fco[i] = (n < NO_) ? (f16)ldin(fcw, k*NO_ + n, fl) : (f16)0.f;
    return;
  }
  i -= FCO_ELEMS;
  if (i < BIAS_ELEMS) {
    int g = i >> 10;
    const void* b = (g==0) ? bfv : (g==1) ? biv : (g==2) ? bov : bcv;
    bias[i] = ldin(b, i & 1023, fl);
    return;
  }
  i -= BIAS_ELEMS;
  if (i < OB_ELEMS) {
    ob[i] = (i < NO_) ? ldin(fcb, i, fl) : 0.f;
  }
}

// G = x_chunk @ Wx^T-layout + bias : M=1024, N=4096, K=512.
// Conversion (fp32/bf16 dual-path) fused into the A-fragment load.
__global__ __launch_bounds__(256) void gemm_g(
    const void* __restrict__ X, int xoff, const int* __restrict__ flagp,
    const unsigned short* __restrict__ Wx,
    const float* __restrict__ bias,
    f16* __restrict__ G)
{
  const int fl = *flagp;
  const int lane = threadIdx.x & 63, w = threadIdx.x >> 6;
  const int lo = lane & 15, quad = lane >> 4;
  const int m0 = blockIdx.x * 128 + (w >> 1) * 64;
  const int n0 = blockIdx.y * 128 + (w & 1) * 64;
  f32x4 acc[4][4] = {};
  for (int k0 = 0; k0 < F_; k0 += 32) {
    bf16x8 a[4], b[4];
    if (fl) {
      #pragma unroll
      for (int mt = 0; mt < 4; mt++) {
        const float* src = (const float*)X + xoff + (size_t)(m0 + 16*mt + lo) * F_ + k0 + quad*8;
        f32x4 v0 = *(const f32x4*)(src);
        f32x4 v1 = *(const f32x4*)(src + 4);
        #pragma unroll
        for (int j = 0; j < 4; j++) {
          a[mt][j]   = (short)f2bf(v0[j]);
          a[mt][4+j] = (short)f2bf(v1[j]);
        }
      }
    } else {
      #pragma unroll
      for (int mt = 0; mt < 4; mt++)
        a[mt] = *(const bf16x8*)((const unsigned short*)X + xoff + (size_t)(m0 + 16*mt + lo) * F_ + k0 + quad*8);
    }
    #pragma unroll
    for (int nt = 0; nt < 4; nt++)
      b[nt] = *(const bf16x8*)(Wx + (size_t)(n0 + 16*nt + lo) * F_ + k0 + quad*8);
    #pragma unroll
    for (int mt = 0; mt < 4; mt++)
      #pragma unroll
      for (int nt = 0; nt < 4; nt++)
        acc[mt][nt] = __builtin_amdgcn_mfma_f32_16x16x32_bf16(a[mt], b[nt], acc[mt][nt], 0, 0, 0);
  }
  #pragma unroll
  for (int mt = 0; mt < 4; mt++)
    #pragma unroll
    for (int nt = 0; nt < 4; nt++)
      #pragma unroll
      for (int r = 0; r < 4; r++) {
        int row = m0 + 16*mt + quad*4 + r;
        int col = n0 + 16*nt + lo;
        G[(size_t)row * NG_ + col] = (f16)(acc[mt][nt][r] + bias[col]);
      }
}

// Persistent cooperative recurrence for one 16-step chunk.
// 128 blocks x 256 thr (4 waves). Block owns cols jb..jb+8 for ALL 4 gates.
// Barrier: per-block arrival flags (64B-spaced, sc0/sc1), wave-parallel poll.
__global__ __launch_bounds__(256) void recur_coop(
    const f16* __restrict__ U, const f16* __restrict__ Gc,
    f16* __restrict__ Ht, float* __restrict__ Cst,
    int* __restrict__ flags, int base)
{
  __shared__ f16 Usm[32768];  // 64 KB: frag f = ki*2+nt (64), 512 f16 each
  const int blk = blockIdx.x;
  const int jb = blk * 8;
  const int tid = threadIdx.x;
  const int lane = tid & 63, w = tid >> 6;
  const int lo = lane & 15, quad = lane >> 4;
  const int m0 = w * 16;

  // stage U-slice into LDS, frag-ordered (once per launch)
  #pragma unroll
  for (int j = 0; j < 16; j++) {
    int u = tid + j*256;              // 4096 16B-units
    int lp = u & 63, f = u >> 6;
    int ki = f >> 1, nt = f & 1;
    int n = nt*16 + (lp & 15), qd = lp >> 4;
    int row = (n >> 3)*H_ + jb + (n & 7);
    *(f16x8*)(Usm + f*512 + lp*8) =
        *(const f16x8*)(U + (size_t)row*H_ + ki*32 + qd*8);
  }
  const int c = lane & 7, hi = (lane >> 3) & 1;
  const int colg = jb + c;
  const int b0r = m0 + quad*4 + hi*2;
  float creg[2];
  creg[0] = Cst[(size_t)b0r*H_ + colg];
  creg[1] = Cst[(size_t)(b0r+1)*H_ + colg];
  __syncthreads();

  // preload G preacts for s=0 (bias already folded in)
  float gv[2][4];
  {
    const f16* gg0 = Gc + ((size_t)b0r)*NG_ + colg;
    #pragma unroll
    for (int g = 0; g < 4; g++) {
      gv[0][g] = (float)gg0[g*1024];
      gv[1][g] = (float)gg0[NG_ + g*1024];
    }
  }

  for (int s = 0; s < CHUNK_; s++) {
    const f16* Ap = Ht + (size_t)s*B_*H_ + (size_t)(m0 + lo)*H_ + quad*8;
    f16x8 a0[8], a1[8], a2[8], a3[8];
    drain_vmem();               // exact vmcnt bookkeeping from here
    load_a8_nw(Ap,       a0);
    load_a8_nw(Ap + 256, a1);
    load_a8_nw(Ap + 512, a2);
    load_a8_nw(Ap + 768, a3);
    f32x4 acc0 = {0.f,0.f,0.f,0.f}, acc1 = {0.f,0.f,0.f,0.f};
    WAIT_VM(24);
    #pragma unroll
    for (int u = 0; u < 8; u++) {
      f16x8 bb0 = *(const f16x8*)(Usm + ((u)*2+0)*512 + lane*8);
      f16x8 bb1 = *(const f16x8*)(Usm + ((u)*2+1)*512 + lane*8);
      acc0 = __builtin_amdgcn_mfma_f32_16x16x32_f16(a0[u], bb0, acc0, 0, 0, 0);
      acc1 = __builtin_amdgcn_mfma_f32_16x16x32_f16(a0[u], bb1, acc1, 0, 0, 0);
    }
    WAIT_VM(16);
    #pragma unroll
    for (int u = 0; u < 8; u++) {
      f16x8 bb0 = *(const f16x8*)(Usm + ((8+u)*2+0)*512 + lane*8);
      f16x8 bb1 = *(const f16x8*)(Usm + ((8+u)*2+1)*512 + lane*8);
      acc0 = __builtin_amdgcn_mfma_f32_16x16x32_f16(a1[u], bb0, acc0, 0, 0, 0);
      acc1 = __builtin_amdgcn_mfma_f32_16x16x32_f16(a1[u], bb1, acc1, 0, 0, 0);
    }
    WAIT_VM(8);
    #pragma unroll
    for (int u = 0; u < 8; u++) {
      f16x8 bb0 = *(const f16x8*)(Usm + ((16+u)*2+0)*512 + lane*8);
      f16x8 bb1 = *(const f16x8*)(Usm + ((16+u)*2+1)*512 + lane*8);
      acc0 = __builtin_amdgcn_mfma_f32_16x16x32_f16(a2[u], bb0, acc0, 0, 0, 0);
      acc1 = __builtin_amdgcn_mfma_f32_16x16x32_f16(a2[u], bb1, acc1, 0, 0, 0);
    }
    WAIT_VM(0);
    #pragma unroll
    for (int u = 0; u < 8; u++) {
      f16x8 bb0 = *(const f16x8*)(Usm + ((24+u)*2+0)*512 + lane*8);
      f16x8 bb1 = *(const f16x8*)(Usm + ((24+u)*2+1)*512 + lane*8);
      acc0 = __builtin_amdgcn_mfma_f32_16x16x32_f16(a3[u], bb0, acc0, 0, 0, 0);
      acc1 = __builtin_amdgcn_mfma_f32_16x16x32_f16(a3[u], bb1, acc1, 0, 0, 0);
    }
    // prefetch next-step G (normal cached loads; drained before barrier)
    float gn[2][4];
    if (s + 1 < CHUNK_) {
      const f16* gg0 = Gc + ((size_t)((s+1)*B_ + b0r))*NG_ + colg;
      #pragma unroll
      for (int g = 0; g < 4; g++) {
        gn[0][g] = (float)gg0[g*1024];
        gn[1][g] = (float)gg0[NG_ + g*1024];
      }
    }
    // gate-combine in-wave (C-layout: col=lane&15, row=quad*4+r)
    f16* Hn = Ht + (size_t)(s+1)*B_*H_;
    #pragma unroll
    for (int e = 0; e < 2; e++) {
      int src = quad*16 + c;
      float f_lo = __shfl(acc0[e],   src);
      float f_hi = __shfl(acc0[2+e], src);
      float i_lo = __shfl(acc0[e],   src + 8);
      float i_hi = __shfl(acc0[2+e], src + 8);
      float o_lo = __shfl(acc1[e],   src);
      float o_hi = __shfl(acc1[2+e], src);
      float a_lo = __shfl(acc1[e],   src + 8);
      float a_hi = __shfl(acc1[2+e], src + 8);
      float pf = (hi ? f_hi : f_lo) + gv[e][0];
      float pi = (hi ? i_hi : i_lo) + gv[e][1];
      float po = (hi ? o_hi : o_lo) + gv[e][2];
      float pa = (hi ? a_hi : a_lo) + gv[e][3];
      float vf = sigm(pf), vi = sigm(pi), vo = sigm(po);
      creg[e] = vi * tanh_(pa) + vf * creg[e];
      float hn = vo * tanh_(creg[e]);
      store_h_sys(Hn + (size_t)(b0r + e)*H_ + colg, (f16)hn);
    }
    if (s + 1 < CHUNK_) {
      drain_vmem();             // h stores acked at IF$ + gn arrived
      __syncthreads();
      const int target = base + s + 1;
      if (tid == 0) store_flag_sys(flags + blk*16, target);
      if (w == 0) {
        const int* fp0 = flags + (2*lane)*16;
        const int* fp1 = flags + (2*lane+1)*16;
        int f0, f1;
        do {
          load_flag2_sys(fp0, fp1, f0, f1);
        } while (!__all(f0 >= target && f1 >= target));
      }
      __syncthreads();
      #pragma unroll
      for (int e = 0; e < 2; e++)
        #pragma unroll
        for (int g = 0; g < 4; g++) gv[e][g] = gn[e][g];
    }
  }
  Cst[(size_t)b0r*H_ + colg]     = creg[0];
  Cst[(size_t)(b0r+1)*H_ + colg] = creg[1];
}

// out = Hall[1..128] @ Fco^T-layout + ob : M=8192, N=640(pad), K=1024, fp32 out
__global__ __launch_bounds__(256) void gemm_out(
    const f16* __restrict__ A,
    const f16* __restrict__ Bt,
    const float* __restrict__ ob,
    float* __restrict__ out)
{
  const int lane = threadIdx.x & 63, w = threadIdx.x >> 6;
  const int lo = lane & 15, quad = lane >> 4;
  const int m0 = blockIdx.x * 128 + (w >> 1) * 64;
  const int n0 = blockIdx.y * 128 + (w & 1) * 64;
  f32x4 acc[4][4] = {};
  #pragma unroll 2
  for (int k0 = 0; k0 < H_; k0 += 32) {
    f16x8 a[4], b[4];
    #pragma unroll
    for (int mt = 0; mt < 4; mt++)
      a[mt] = *(const f16x8*)(A + (size_t)(m0 + 16*mt + lo) * H_ + k0 + quad*8);
    #pragma unroll
    for (int nt = 0; nt < 4; nt++)
      b[nt] = *(const f16x8*)(Bt + (size_t)(n0 + 16*nt + lo) * H_ + k0 + quad*8);
    #pragma unroll
    for (int mt = 0; mt < 4; mt++)
      #pragma unroll
      for (int nt = 0; nt < 4; nt++)
        acc[mt][nt] = __builtin_amdgcn_mfma_f32_16x16x32_f16(a[mt], b[nt], acc[mt][nt], 0, 0, 0);
  }
  #pragma unroll
  for (int mt = 0; mt < 4; mt++)
    #pragma unroll
    for (int nt = 0; nt < 4; nt++)
      #pragma unroll
      for (int r = 0; r < 4; r++) {
        int row = m0 + 16*mt + quad*4 + r;
        int col = n0 + 16*nt + lo;
        if (col < NO_)
          out[(size_t)row * NO_ + col] = acc[mt][nt][r] + ob[col];
      }
}

extern "C" void kernel_launch(void* const* d_in, const int* in_sizes, int n_in,
                              void* d_out, int out_size, void* d_ws, size_t ws_size,
                              hipStream_t stream)
{
  const void* x   = d_in[0];
  const void* wfw = d_in[1];  const void* wfb = d_in[2];
  const void* wiw = d_in[3];  const void* wib = d_in[4];
  const void* wow = d_in[5];  const void* wob = d_in[6];
  const void* wcw = d_in[7];  const void* wcb = d_in[8];
  const void* ufw = d_in[9];  const void* uiw = d_in[10];
  const void* uow = d_in[11]; const void* ucw = d_in[12];
  const void* fcw = d_in[13]; const void* fcb = d_in[14];

  char* ws = (char*)d_ws;
  unsigned short* Wx = (unsigned short*)(ws + 0);        //  4,194,304 B
  f16*   U    = (f16*)  (ws + 4194304);                  //  8,388,608 B
  f16*   Fco  = (f16*)  (ws + 12582912);                 //  1,310,720 B
  f16*   G    = (f16*)  (ws + 13893632);                 //  8,388,608 B
  f16*   Hall = (f16*)  (ws + 22282240);                 // 16,908,288 B (129 states)
  float* C    = (float*)(ws + 39190528);                 //    262,144 B
  float* bias = (float*)(ws + 39452672);                 //     16,384 B
  float* ob   = (float*)(ws + 39469056);                 //      2,560 B
  int*   flags= (int*)  (ws + 39471616);                 //      8,192 B (128 x 64B)
  int*   flag = (int*)  (ws + 39479808);                 //          4 B
  if (ws_size < 39479812u) return;

  hipMemsetAsync(Hall, 0, (size_t)B_*H_*sizeof(f16), stream);  // h_{-1} = 0
  hipMemsetAsync(C, 0, (size_t)B_*H_*sizeof(float), stream);   // c_{-1} = 0
  hipMemsetAsync(flags, 0, NBLK_R*16*sizeof(int), stream);     // arrival flags

  detect_kernel<<<1, 256, 0, stream>>>((const unsigned short*)x, flag);

  pack_kernel<<<(PACK_TOTAL + 255)/256, 256, 0, stream>>>(
      wfw, wiw, wow, wcw, wfb, wib, wob, wcb, ufw, uiw, uow, ucw, fcw, fcb,
      flag, Wx, U, Fco, bias, ob);

  for (int cch = 0; cch < T_/CHUNK_; cch++) {
    gemm_g<<<dim3(8, 32), 256, 0, stream>>>(
        x, cch * CHUNK_*B_*F_, flag, Wx, bias, G);
    {
      const f16* Up = U;
      const f16* Gp = G;
      f16* Htp = Hall + (size_t)cch*CHUNK_*B_*H_;
      float* Cp = C;
      int* flp = flags;
      int base = cch * CHUNK_;
      void* args[] = {&Up, &Gp, &Htp, &Cp, &flp, &base};
      hipLaunchCooperativeKernel((const void*)recur_coop, dim3(NBLK_R), dim3(256),
                                 args, 0, stream);
    }
  }
  gemm_out<<<dim3(64, 5), 256, 0, stream>>>(Hall + (size_t)B_*H_, Fco, ob, (float*)d_out);
}